// Round 4
// baseline (344.707 us; speedup 1.0000x reference)
//
#include <hip/hip_runtime.h>
#include <hip/hip_bf16.h>

// RoleSensitiveEmbedding: out[t,:] = W_{role[t]} @ emb[ids[t],:]
// R6 (resubmit — prior round hit GPUAcquisitionTimeout, never measured):
// fuse gather into GEMM *without* R4's mistakes. A-tile is reg-staged:
// load 32B fp32 from emb[tokid[row]], cvt->bf16 IN REGISTERS (staging path),
// ds_write_b128 the exact same swizzled bf16 LDS image R3/R5 used. Fragment
// reads + MFMA + epilogue are unchanged from the proven 326us kernel. B stays
// on global_load_lds. k_gather and the X buffer are deleted (-20us serial
// wall time, -66MB HBM). k_pre records tokid[row]=ids[perm[row]] so the
// GEMM's indirection hoists out of the K-loop. 1 memset + 2 kernels.

#define M_TOK   16384
#define DIM     1024
#define MT      128                 // gemm m-tile rows
#define NTIL    130                 // ceil(n0/128)+ceil(n1/128) <= 130 always
#define XROWS   (NTIL * MT)         // 16640
#define BK      64
#define PBLK    64                  // partition blocks (64*256 = 16384 tokens)
#define WBLKS   2048                // 2*1024*1024 floats / (256 thr * 4)

typedef __attribute__((ext_vector_type(8))) short short8;
typedef __attribute__((ext_vector_type(4))) float f32x4;

// ---- workspace layout (bytes) ----
#define OFF_TOK  256                // tokid[XROWS] : 66560 B
#define OFF_PERM 66816              // perm[XROWS]  : 66560 B
#define OFF_WB   133376             // Wb: 2*1024*1024 bf16 = 4 MB
// total ~4.33 MB ; memset covers [0, OFF_PERM) = cnt + tokid

static __device__ __forceinline__ unsigned short f2bf(float f) {
    unsigned int u = __float_as_uint(f);
    u += 0x7fffu + ((u >> 16) & 1u);   // round-to-nearest-even
    return (unsigned short)(u >> 16);
}

static __device__ __forceinline__ unsigned int pk2(float a, float b) {
    __hip_bfloat162 h = __float22bfloat162_rn(make_float2(a, b));   // RNE, same as f2bf
    union { __hip_bfloat162 h; unsigned int u; } c;
    c.h = h;
    return c.u;
}

// blocks [0,PBLK): role partition via two-sided atomic packing; also records
// tokid[row] = ids[t] so the GEMM needs no second indirection.
// blocks [PBLK, PBLK+WBLKS): convert W0|W1 fp32 -> bf16 Wb
__global__ void k_pre(const int* __restrict__ role, const int* __restrict__ ids,
                      int* perm, int* tokid, int* cnt,
                      const float* __restrict__ W0, const float* __restrict__ W1,
                      unsigned short* __restrict__ Wb) {
    int b = blockIdx.x;
    if (b < PBLK) {
        int t = b * 256 + threadIdx.x;           // 0..16383
        int row;
        if (role[t] == 1) { int s = atomicAdd(&cnt[1], 1); row = XROWS - 1 - s; }
        else              { int s = atomicAdd(&cnt[0], 1); row = s; }
        perm[row]  = t;
        tokid[row] = ids[t];
    } else {
        int idx = ((b - PBLK) * 256 + threadIdx.x) * 4;   // 0 .. 2*1048576-4
        const float* src = (idx < 1048576) ? (W0 + idx) : (W1 + (idx - 1048576));
        float4 f = *(const float4*)src;
        *(ushort4*)(Wb + idx) = make_ushort4(f2bf(f.x), f2bf(f.y), f2bf(f.z), f2bf(f.w));
    }
}

// 128x128 tile GEMM, C = A * B^T.
//   A: emb rows gathered on the fly; fp32 32B/slot loaded to regs, cvt'd to
//      bf16 in regs, ds_write_b128 into the SAME swizzled bf16 layout as R3
//      (LDS image identical -> fragment path untouched).
//   B: Wb rows via global_load_lds width=16 (unchanged).
// Gap rows: tokid==0 -> emb row 0 (the all-zero padding row): safe addresses,
// garbage never stored (epilogue bounds-guards the scatter).
__global__ __launch_bounds__(256, 3)
void k_gemm(const float* __restrict__ emb, const unsigned short* __restrict__ Wbu,
            const int* __restrict__ perm, const int* __restrict__ tokid,
            const int* __restrict__ cnt, float* __restrict__ out) {
    __shared__ short As[MT * BK];      // 16 KB
    __shared__ short Bs[MT * BK];      // 16 KB

    // XCD swizzle: all 8 n-tiles of an m-tile share one XCD's L2
    int f  = blockIdx.x;
    int mt = ((f >> 6) << 3) | (f & 7);
    int nt = (f >> 3) & 7;
    if (mt >= NTIL) return;

    int n0 = cnt[0], n1 = cnt[1];
    int T0 = (n0 + 127) >> 7, T1 = (n1 + 127) >> 7;
    int e, lo, hi;
    if (mt < T0)              { e = 0; lo = 0;            hi = n0;    }
    else if (mt >= NTIL - T1) { e = 1; lo = XROWS - n1;   hi = XROWS; }
    else return;                           // gap tile

    const short* Bg = (const short*)Wbu + (size_t)e * DIM * DIM + (size_t)nt * MT * DIM;
    const char*  embB = (const char*)emb;

    int tid  = threadIdx.x;
    int lane = tid & 63;
    int w    = tid >> 6;         // wave 0..3
    int wm   = w & 1, wn = w >> 1;
    int quad = lane >> 4, lq = lane & 15;

    // Per-thread staging metadata, K-loop-invariant. Slot s=(w*4+i)*64+lane
    // covers LDS 16B slot s; row = s>>3; source k-chunk kc = (s&7)^(row&7)
    // (swizzle applied on SOURCE side; LDS stays linear in s — rule #21 pair
    // with the existing swizzled fragment reads).
    unsigned int aoff[4];     // byte offset into emb (fp32): tok*4096 + kc*32
    unsigned int boff[4];     // byte offset into Bg (bf16)
    int sA[4];
#pragma unroll
    for (int i = 0; i < 4; ++i) {
        int s   = (w * 4 + i) * 64 + lane;
        int row = s >> 3;
        int kc  = (s & 7) ^ (row & 7);
        sA[i]   = s;
        aoff[i] = (unsigned int)tokid[mt * MT + row] * (DIM * 4) + (unsigned int)kc * 32;
        boff[i] = (unsigned int)(row * DIM + kc * 8) * 2;
    }

    f32x4 acc[4][4] = {};

    for (int k0 = 0; k0 < DIM; k0 += BK) {
        // A: issue 8 fp32 16B loads (independent, overlap with B issue below)
        float4 fa[4][2];
#pragma unroll
        for (int i = 0; i < 4; ++i) {
            const char* p = embB + aoff[i] + (unsigned int)k0 * 4;
            fa[i][0] = *(const float4*)(p);
            fa[i][1] = *(const float4*)(p + 16);
        }
        // B: async global->LDS (unchanged path)
#pragma unroll
        for (int i = 0; i < 4; ++i) {
            __builtin_amdgcn_global_load_lds(
                (const __attribute__((address_space(1))) unsigned int*)((const char*)Bg + boff[i] + (unsigned int)k0 * 2),
                (__attribute__((address_space(3))) unsigned int*)(&Bs[sA[i] * 8]),
                16, 0, 0);
        }
        // A: cvt in regs (staging path, NOT fragment path) + ds_write_b128
#pragma unroll
        for (int i = 0; i < 4; ++i) {
            union { unsigned int u[4]; short8 v; } cv;
            cv.u[0] = pk2(fa[i][0].x, fa[i][0].y);
            cv.u[1] = pk2(fa[i][0].z, fa[i][0].w);
            cv.u[2] = pk2(fa[i][1].x, fa[i][1].y);
            cv.u[3] = pk2(fa[i][1].z, fa[i][1].w);
            *(short8*)&As[sA[i] * 8] = cv.v;
        }
        __syncthreads();

        // ---- fragment reads + MFMA: byte-identical to the 326us kernel ----
#pragma unroll
        for (int s = 0; s < 2; ++s) {
            short8 av[4], bv[4];
            int s4q = s * 4 + quad;
#pragma unroll
            for (int i = 0; i < 4; ++i) {
                int ra = wm * 64 + i * 16 + lq;
                av[i] = *(const short8*)&As[(ra * 8 + (s4q ^ (ra & 7))) * 8];
                int rb = wn * 64 + i * 16 + lq;
                bv[i] = *(const short8*)&Bs[(rb * 8 + (s4q ^ (rb & 7))) * 8];
            }
#pragma unroll
            for (int i = 0; i < 4; ++i)
#pragma unroll
                for (int j = 0; j < 4; ++j)
                    acc[i][j] = __builtin_amdgcn_mfma_f32_16x16x32_bf16(
                        av[i], bv[j], acc[i][j], 0, 0, 0);
        }
        __syncthreads();
    }

    // epilogue: C/D map m = quad*4+reg, n = lq; scatter rows to out[token,:]
    int colbase = nt * 128 + wn * 64 + lq;
#pragma unroll
    for (int i = 0; i < 4; ++i) {
#pragma unroll
        for (int r = 0; r < 4; ++r) {
            int mrow = mt * MT + wm * 64 + i * 16 + quad * 4 + r;
            if (mrow < lo || mrow >= hi) continue;   // gap row (bounds, not sentinel)
            int token = perm[mrow];
            float* o = out + (size_t)token * DIM + colbase;
#pragma unroll
            for (int j = 0; j < 4; ++j)
                o[j * 16] = acc[i][j][r];
        }
    }
}

extern "C" void kernel_launch(void* const* d_in, const int* in_sizes, int n_in,
                              void* d_out, int out_size, void* d_ws, size_t ws_size,
                              hipStream_t stream) {
    const int*   ids  = (const int*)d_in[0];
    const int*   role = (const int*)d_in[1];
    const float* emb  = (const float*)d_in[2];
    const float* W0   = (const float*)d_in[3];
    const float* W1   = (const float*)d_in[4];
    float*       out  = (float*)d_out;

    char* ws = (char*)d_ws;
    int* cnt   = (int*)ws;
    int* tokid = (int*)(ws + OFF_TOK);
    int* perm  = (int*)(ws + OFF_PERM);
    unsigned short* Wb = (unsigned short*)(ws + OFF_WB);

    // zero cnt + tokid (gap rows must point at emb row 0, the zero pad row)
    hipMemsetAsync(ws, 0x00, OFF_PERM, stream);
    k_pre <<<PBLK + WBLKS, 256, 0, stream>>>(role, ids, perm, tokid, cnt, W0, W1, Wb);
    k_gemm<<<1088,         256, 0, stream>>>(emb, Wb, perm, tokid, cnt, out);
}

// Round 5
// 322.307 us; speedup vs baseline: 1.0695x; 1.0695x over previous
//
#include <hip/hip_runtime.h>

// RoleSensitiveEmbedding: out[t,:] = W_{role[t]} @ emb[ids[t],:]
// R7: consolidate to 2 kernels. Token-ordered X (X[t] = bf16(emb[ids[t]]))
// removes gather's dependency on the partition, so partition + W-convert +
// gather merge into ONE pre-kernel (block-range split; all independent, all
// HBM-bound -> overlap). The GEMM takes the perm indirection instead, hoisted
// into its per-thread staging offsets before the K-loop (zero inner-loop
// cost). GEMM LDS image / inner loop / MFMA / epilogue byte-identical to the
// proven R3/R5 326-332us kernel. 1 memset + 2 kernels.
//
// Ledger: R3=326.3 R5=332.0 (3-kernel anchor) | R4=345.6 R6=344.7 (fused
// gather = 8x emb re-fetch, rejected).

#define M_TOK   16384
#define DIM     1024
#define MT      128                 // gemm m-tile rows
#define NTIL    130                 // ceil(n0/128)+ceil(n1/128) <= 130 always
#define XROWS   (NTIL * MT)         // 16640 (virtual staged-row space)
#define BK      64
#define PBLK    64                  // partition blocks (64*256 = 16384 tokens)
#define WBLKS   2048                // 2*1024*1024 floats / (256 thr * 4)
#define GROWS   8                   // gather rows per block
#define GBLK    (M_TOK / GROWS)     // 2048 gather blocks

typedef __attribute__((ext_vector_type(8))) short short8;
typedef __attribute__((ext_vector_type(4))) float f32x4;

// ---- workspace layout (bytes) ----
#define OFF_PERM 256                // perm[XROWS]  : 66560 B
#define OFF_WB   66816              // Wb: 2*1024*1024 bf16 = 4 MB
#define OFF_X    4261120            // X: 16384*1024 bf16 = 32 MB (token order)
// total ~37.8 MB

static __device__ __forceinline__ unsigned short f2bf(float f) {
    unsigned int u = __float_as_uint(f);
    u += 0x7fffu + ((u >> 16) & 1u);   // round-to-nearest-even
    return (unsigned short)(u >> 16);
}

// blocks [0,PBLK):               role partition via two-sided atomic packing
// blocks [PBLK, PBLK+WBLKS):     convert W0|W1 fp32 -> bf16 Wb
// blocks [PBLK+WBLKS, +GBLK):    gather X[t] = bf16(emb[ids[t]]), token order
// All three are mutually independent -> merged into one launch; the scattered
// gather reads overlap the streaming W-convert instead of serializing.
__global__ void k_pre(const int* __restrict__ role, const int* __restrict__ ids,
                      int* perm, int* cnt,
                      const float* __restrict__ W0, const float* __restrict__ W1,
                      unsigned short* __restrict__ Wb,
                      const float* __restrict__ emb, unsigned short* __restrict__ X) {
    int b = blockIdx.x;
    if (b < PBLK) {
        int t = b * 256 + threadIdx.x;           // 0..16383
        int row;
        if (role[t] == 1) { int s = atomicAdd(&cnt[1], 1); row = XROWS - 1 - s; }
        else              { int s = atomicAdd(&cnt[0], 1); row = s; }
        perm[row] = t;
    } else if (b < PBLK + WBLKS) {
        int idx = ((b - PBLK) * 256 + threadIdx.x) * 4;   // 0 .. 2*1048576-4
        const float* src = (idx < 1048576) ? (W0 + idx) : (W1 + (idx - 1048576));
        float4 f = *(const float4*)src;
        *(ushort4*)(Wb + idx) = make_ushort4(f2bf(f.x), f2bf(f.y), f2bf(f.z), f2bf(f.w));
    } else {
        int t0  = (b - PBLK - WBLKS) * GROWS;
        int tid = threadIdx.x;
#pragma unroll
        for (int r = 0; r < GROWS; ++r) {
            int tok = t0 + r;                    // 0..16383, dense
            int id  = ids[tok];                  // block-uniform scalar load
            float4 f = *(const float4*)(emb + (size_t)id * DIM + tid * 4);
            *(ushort4*)(X + (size_t)tok * DIM + tid * 4) =
                make_ushort4(f2bf(f.x), f2bf(f.y), f2bf(f.z), f2bf(f.w));
        }
    }
}

// 128x128 tile GEMM, C = A * B^T: A = X rows selected via perm (hoisted),
// B^T = W_e rows. LDS staged via global_load_lds width=16, XOR swizzle
// kc^(row&7) on the global SOURCE side so ds_read_b128 fragment reads stay
// ~conflict-free (LDS image byte-identical to the proven R3/R5 kernel).
__global__ __launch_bounds__(256, 3)
void k_gemm(const unsigned short* __restrict__ Xu, const unsigned short* __restrict__ Wbu,
            const int* __restrict__ perm, const int* __restrict__ cnt,
            float* __restrict__ out) {
    __shared__ short As[MT * BK];      // 16 KB
    __shared__ short Bs[MT * BK];      // 16 KB

    // XCD swizzle: all 8 n-tiles of an m-tile share one XCD's L2
    int f  = blockIdx.x;
    int mt = ((f >> 6) << 3) | (f & 7);
    int nt = (f >> 3) & 7;
    if (mt >= NTIL) return;

    int n0 = cnt[0], n1 = cnt[1];
    int T0 = (n0 + 127) >> 7, T1 = (n1 + 127) >> 7;
    int e, lo, hi;
    if (mt < T0)              { e = 0; lo = 0;            hi = n0;    }
    else if (mt >= NTIL - T1) { e = 1; lo = XROWS - n1;   hi = XROWS; }
    else return;                           // gap tile

    const short* Xg = (const short*)Xu;
    const short* Bg = (const short*)Wbu + (size_t)e * DIM * DIM + (size_t)nt * MT * DIM;

    int tid  = threadIdx.x;
    int lane = tid & 63;
    int w    = tid >> 6;         // wave 0..3
    int wm   = w & 1, wn = w >> 1;
    int quad = lane >> 4, lq = lane & 15;

    // Hoisted staging offsets (K-loop-invariant). LDS 16B slot s=(w*4+i)*64+
    // lane; row = s>>3; source k-chunk kc = (s&7)^(row&7) (swizzle on SOURCE
    // side, LDS linear — pairs with the swizzled fragment reads below).
    // A-row indirection prow = perm[staged row] hoists here; gap rows -> X
    // row 0 (valid memory; garbage never stored, epilogue bounds-guards).
    unsigned int aoff[4], boff[4];
    int sA[4];
#pragma unroll
    for (int i = 0; i < 4; ++i) {
        int s    = (w * 4 + i) * 64 + lane;
        int row  = s >> 3;
        int kc   = (s & 7) ^ (row & 7);
        int grow = mt * MT + row;
        int prow = (grow >= lo && grow < hi) ? perm[grow] : 0;
        sA[i]   = s;
        aoff[i] = (unsigned int)prow * DIM + (unsigned int)kc * 8;   // elements
        boff[i] = (unsigned int)(row * DIM + kc * 8);                // elements
    }

    f32x4 acc[4][4] = {};

    for (int k0 = 0; k0 < DIM; k0 += BK) {
#pragma unroll
        for (int i = 0; i < 4; ++i) {
            __builtin_amdgcn_global_load_lds(
                (const __attribute__((address_space(1))) unsigned int*)(Xg + aoff[i] + k0),
                (__attribute__((address_space(3))) unsigned int*)(&As[sA[i] * 8]),
                16, 0, 0);
            __builtin_amdgcn_global_load_lds(
                (const __attribute__((address_space(1))) unsigned int*)(Bg + boff[i] + k0),
                (__attribute__((address_space(3))) unsigned int*)(&Bs[sA[i] * 8]),
                16, 0, 0);
        }
        __syncthreads();

        // ---- fragment reads + MFMA: byte-identical to the 326us kernel ----
#pragma unroll
        for (int s = 0; s < 2; ++s) {
            short8 av[4], bv[4];
            int s4q = s * 4 + quad;
#pragma unroll
            for (int i = 0; i < 4; ++i) {
                int ra = wm * 64 + i * 16 + lq;
                av[i] = *(const short8*)&As[(ra * 8 + (s4q ^ (ra & 7))) * 8];
                int rb = wn * 64 + i * 16 + lq;
                bv[i] = *(const short8*)&Bs[(rb * 8 + (s4q ^ (rb & 7))) * 8];
            }
#pragma unroll
            for (int i = 0; i < 4; ++i)
#pragma unroll
                for (int j = 0; j < 4; ++j)
                    acc[i][j] = __builtin_amdgcn_mfma_f32_16x16x32_bf16(
                        av[i], bv[j], acc[i][j], 0, 0, 0);
        }
        __syncthreads();
    }

    // epilogue: C/D map m = quad*4+reg, n = lq; scatter rows to out[token,:]
    int colbase = nt * 128 + wn * 64 + lq;
#pragma unroll
    for (int i = 0; i < 4; ++i) {
#pragma unroll
        for (int r = 0; r < 4; ++r) {
            int mrow = mt * MT + wm * 64 + i * 16 + quad * 4 + r;
            if (mrow < lo || mrow >= hi) continue;   // gap row (bounds, not sentinel)
            int token = perm[mrow];
            float* o = out + (size_t)token * DIM + colbase;
#pragma unroll
            for (int j = 0; j < 4; ++j)
                o[j * 16] = acc[i][j][r];
        }
    }
}

extern "C" void kernel_launch(void* const* d_in, const int* in_sizes, int n_in,
                              void* d_out, int out_size, void* d_ws, size_t ws_size,
                              hipStream_t stream) {
    const int*   ids  = (const int*)d_in[0];
    const int*   role = (const int*)d_in[1];
    const float* emb  = (const float*)d_in[2];
    const float* W0   = (const float*)d_in[3];
    const float* W1   = (const float*)d_in[4];
    float*       out  = (float*)d_out;

    char* ws = (char*)d_ws;
    int* cnt  = (int*)ws;
    int* perm = (int*)(ws + OFF_PERM);
    unsigned short* Wb = (unsigned short*)(ws + OFF_WB);
    unsigned short* X  = (unsigned short*)(ws + OFF_X);

    hipMemsetAsync(cnt, 0x00, 2 * sizeof(int), stream);
    k_pre <<<PBLK + WBLKS + GBLK, 256, 0, stream>>>(role, ids, perm, cnt, W0, W1, Wb, emb, X);
    k_gemm<<<1088,                256, 0, stream>>>(X, Wb, perm, cnt, out);
}